// Round 3
// baseline (109.902 us; speedup 1.0000x reference)
//
#include <hip/hip_runtime.h>

// VolumeRenderer R13: checkpointed walk — kill the prewalk redundancy.
// R12 post-mortem: a -25% VALU diet gave only -7.4% => volrend_seg is not
// purely issue-bound; and the NSEG frame has two structural sinks:
//  (a) prewalk redundancy: segs re-walk 48+96+144 = 288 steps/ray (60% of
//      all geometry);
//  (b) SIMD pinning: wave w -> SIMD w&3, so ALL seg-3 waves (192 steps)
//      land on SIMD 3 while SIMD 0 does 48 -> 1.6x per-SIMD imbalance.
// R13: a prep kernel (1 thread = 1 ray) walks 144 steps ONCE with the
// bit-identical geom_step/PIPE-chunk sequence and stores t48/t96/t144.
// Render waves load their checkpoint and do exactly 48 render steps each:
// prewalk gone, waves symmetric -> perfect SIMD balance by construction.
// Walk blocks fused into the cvt grid (walk first: serial chain hides under
// the memory-bound cvt). Checkpoints bit-exact => absmax stays 1/256.

constexpr int   R_DIM    = 128;
constexpr int   N_VOX    = R_DIM * R_DIM * R_DIM;
constexpr int   N_STEPS  = 192;
constexpr int   NSEG     = 4;
constexpr int   SEG_LEN  = N_STEPS / NSEG;   // 48
constexpr float STEP_SZ  = 0.001f;
constexpr float CUBE_SZ  = 1.0f / 128.0f;
constexpr int   PIPE     = 8;
constexpr float SIG_MAX  = 5.5f;
constexpr int   CVT_BLOCKS = (N_VOX / 4 + 255) / 256;   // 2048

__device__ __forceinline__ float sigmoid_fast(float x) {
    return __builtin_amdgcn_rcpf(1.0f + __expf(-x));
}

// One geometric DDA step -> cell coords + exact delta. Bit-identical to the
// reference walk. smin==0 exactly (f in [0,1] -> every per-axis lo <= 0).
__device__ __forceinline__ void geom_step(
    float tl, float tmax,
    float oxR, float oyR, float ozR, float dxR, float dyR, float dzR,
    float ix, float iy, float iz, float ipx, float ipy, float ipz,
    int& i0, int& i1, int& i2, float& d)
{
    float px = __fadd_rn(oxR, __fmul_rn(tl, dxR));
    float py = __fadd_rn(oyR, __fmul_rn(tl, dyR));
    float pz = __fadd_rn(ozR, __fmul_rn(tl, dzR));

    // float-domain clamp: med3(floor(p), 0, 127); same value as int clamp
    float c0 = fminf(fmaxf(floorf(px), 0.0f), 127.0f);
    float c1 = fminf(fmaxf(floorf(py), 0.0f), 127.0f);
    float c2 = fminf(fmaxf(floorf(pz), 0.0f), 127.0f);
    i0 = (int)c0;   // dead (DCE'd) in walk-only use
    i1 = (int)c1;
    i2 = (int)c2;

    // t1 = rn((-f)*i) via (c-p) = -f exactly; hi = rn(t1 + max(i,0))
    float t1x = __fmul_rn(__fsub_rn(c0, px), ix);
    float t1y = __fmul_rn(__fsub_rn(c1, py), iy);
    float t1z = __fmul_rn(__fsub_rn(c2, pz), iz);
    float hix = __fadd_rn(t1x, ipx);
    float hiy = __fadd_rn(t1y, ipy);
    float hiz = __fadd_rn(t1z, ipz);
    float smax = fminf(fminf(fminf(hix, hiy), hiz), 1e9f);

    d = __fadd_rn(__fmul_rn(smax, CUBE_SZ), STEP_SZ);
    d = (tl < tmax) ? d : 0.0f;   // inactive -> exact no-op (t frozen)
}

__device__ __forceinline__ void ray_setup(
    const float* __restrict__ origins, const float* __restrict__ dirs, int i,
    float& oxR, float& oyR, float& ozR, float& dxR, float& dyR, float& dzR,
    float& ix, float& iy, float& iz,
    float& ipx, float& ipy, float& ipz,
    float& tmin, float& tmax)
{
    float ox = origins[3 * i + 0];
    float oy = origins[3 * i + 1];
    float oz = origins[3 * i + 2];
    float dx = dirs[3 * i + 0];
    float dy = dirs[3 * i + 1];
    float dz = dirs[3 * i + 2];

    float n2 = __fadd_rn(__fadd_rn(__fmul_rn(dx, dx), __fmul_rn(dy, dy)),
                         __fmul_rn(dz, dz));
    float nrm = sqrtf(n2);
    dx = dx / nrm;
    dy = dy / nrm;
    dz = dz / nrm;

    ix = 1.0f / __fadd_rn(dx, 1e-9f);
    iy = 1.0f / __fadd_rn(dy, 1e-9f);
    iz = 1.0f / __fadd_rn(dz, 1e-9f);

    ipx = fmaxf(ix, 0.0f);
    ipy = fmaxf(iy, 0.0f);
    ipz = fmaxf(iz, 0.0f);

    float t1x = __fmul_rn(-ox, ix), t2x = __fadd_rn(t1x, ix);
    float t1y = __fmul_rn(-oy, iy), t2y = __fadd_rn(t1y, iy);
    float t1z = __fmul_rn(-oz, iz), t2z = __fadd_rn(t1z, iz);
    float lox = fminf(t1x, t2x), hix = fmaxf(t1x, t2x);
    float loy = fminf(t1y, t2y), hiy = fmaxf(t1y, t2y);
    float loz = fminf(t1z, t2z), hiz = fmaxf(t1z, t2z);
    tmin = fmaxf(fmaxf(fmaxf(lox, loy), loz), 0.0f);
    tmax = fminf(fminf(fminf(hix, hiy), hiz), 1e9f);

    // exact *2^7 (scaling lemma keeps the walk bit-identical)
    oxR = __fmul_rn(ox, 128.0f);
    oyR = __fmul_rn(oy, 128.0f);
    ozR = __fmul_rn(oz, 128.0f);
    dxR = __fmul_rn(dx, 128.0f);
    dyR = __fmul_rn(dy, 128.0f);
    dzR = __fmul_rn(dz, 128.0f);
}

__device__ __forceinline__ unsigned pack_voxel(float4 v) {
    unsigned ur = (unsigned)__float2int_rn(sigmoid_fast(v.x) * 255.0f);
    unsigned ug = (unsigned)__float2int_rn(sigmoid_fast(v.y) * 255.0f);
    unsigned ub = (unsigned)__float2int_rn(sigmoid_fast(v.z) * 255.0f);
    unsigned us = (unsigned)__float2int_rn(
        fminf(fmaxf(v.w, 0.0f), SIG_MAX) * (255.0f / SIG_MAX));
    return ur | (ug << 8) | (ub << 16) | (us << 24);
}

// ---- prep: walk blocks first (serial chains start early), then cvt ---------
// walk: thread = ray; 3x48 bit-exact geometry steps -> t48/t96/t144 in cp.
// cvt : thread = 4 z-voxels -> brick-ordered u8x4 (as R11/R12).
__global__ __launch_bounds__(256) void prep(
    const float4* __restrict__ g, uint4* __restrict__ gq4,
    const float* __restrict__ origins, const float* __restrict__ dirs,
    float* __restrict__ cp, int B, int walk_blocks)
{
    if ((int)blockIdx.x < walk_blocks) {
        int r = blockIdx.x * 256 + threadIdx.x;
        if (r >= B) return;

        float oxR, oyR, ozR, dxR, dyR, dzR, ix, iy, iz, ipx, ipy, ipz;
        float tmin, tmax;
        ray_setup(origins, dirs, r, oxR, oyR, ozR, dxR, dyR, dzR,
                  ix, iy, iz, ipx, ipy, ipz, tmin, tmax);

        float t = tmin;
        #pragma unroll
        for (int s = 1; s < NSEG; ++s) {
            for (int c = 0; c < SEG_LEN / PIPE; ++c) {
                if (t >= tmax) break;
                #pragma unroll
                for (int p = 0; p < PIPE; ++p) {
                    int i0, i1, i2; float d;
                    geom_step(t, tmax, oxR, oyR, ozR, dxR, dyR, dzR,
                              ix, iy, iz, ipx, ipy, ipz, i0, i1, i2, d);
                    t = __fadd_rn(t, d);
                }
            }
            cp[(s - 1) * B + r] = t;
        }
        return;
    }

    int tid = (blockIdx.x - walk_blocks) * 256 + threadIdx.x;
    if (tid >= N_VOX / 4) return;
    int zq = tid & 31;              // z-group (4 voxels)
    int y  = (tid >> 5) & 127;
    int x  = tid >> 12;

    int src = (x * R_DIM + y) * R_DIM + 4 * zq;   // float4 index
    float4 v0 = g[src + 0];
    float4 v1 = g[src + 1];
    float4 v2 = g[src + 2];
    float4 v3 = g[src + 3];

    uint4 o;
    o.x = pack_voxel(v0);
    o.y = pack_voxel(v1);
    o.z = pack_voxel(v2);
    o.w = pack_voxel(v3);

    // brick-ordered destination: bid = bx<<10|by<<5|bz, loc = lx<<4|ly<<2|lz
    int bid = ((x >> 2) << 10) | ((y >> 2) << 5) | zq;
    int dst = bid * 16 + (x & 3) * 4 + (y & 3);     // uint4 index
    gq4[dst] = o;
}

// ---- render: 4 symmetric waves/block; wave s renders steps [s*48,s*48+48) --
__global__ __launch_bounds__(256) void volrend_seg(
    const unsigned int* __restrict__ gq,   // brick-ordered u8x4, 8.4 MB
    const float* __restrict__ cp,          // t checkpoints, 3*B floats
    const float* __restrict__ origins,
    const float* __restrict__ dirs,
    float* __restrict__ out,
    int B)
{
    __shared__ float4 lds[64 * (NSEG - 1)];

    int lane = threadIdx.x & 63;
    int seg  = threadIdx.x >> 6;
    int i = blockIdx.x * 64 + lane;

    float oxR, oyR, ozR, dxR, dyR, dzR, ix, iy, iz, ipx, ipy, ipz, tmin, tmax;
    ray_setup(origins, dirs, i, oxR, oyR, ozR, dxR, dyR, dzR,
              ix, iy, iz, ipx, ipy, ipz, tmin, tmax);

    // checkpointed start: no prewalk, waves symmetric
    float t = (seg == 0) ? tmin : cp[(seg - 1) * B + i];

    float light = 1.0f;
    float ar = 0.0f, ag = 0.0f, ab = 0.0f;

    for (int chunk = 0; chunk < SEG_LEN / PIPE; ++chunk) {
        if (t >= tmax) break;

        unsigned int val[PIPE];
        float del[PIPE];
        float tl = t;

        #pragma unroll
        for (int p = 0; p < PIPE; ++p) {
            int i0, i1, i2; float d;
            geom_step(tl, tmax, oxR, oyR, ozR, dxR, dyR, dzR,
                      ix, iy, iz, ipx, ipy, ipz, i0, i1, i2, d);
            unsigned bid = ((unsigned)(i0 >> 2) << 10) |
                           ((unsigned)(i1 >> 2) << 5) |
                           (unsigned)(i2 >> 2);
            unsigned loc = ((unsigned)(i0 & 3) << 4) |
                           ((unsigned)(i1 & 3) << 2) |
                           (unsigned)(i2 & 3);
            val[p] = gq[(bid << 6) | loc];   // dead voxel: sigma-u8==0 -> att=1
            del[p] = d;
            tl = __fadd_rn(tl, d);
        }

        #pragma unroll
        for (int p = 0; p < PIPE; ++p) {
            unsigned int v = val[p];
            // byte-extract casts compile to v_cvt_f32_ubyte0..3
            float r  = (float)(v & 255u);
            float gg = (float)((v >> 8) & 255u);
            float b  = (float)((v >> 16) & 255u);
            float sg = (float)(v >> 24);
            float att = __expf(del[p] * (-SIG_MAX / 255.0f) * sg);
            float w  = light * (1.0f - att);
            float ws = w * (1.0f / 255.0f);
            ar = fmaf(ws, r, ar);
            ag = fmaf(ws, gg, ag);
            ab = fmaf(ws, b, ab);
            light *= att;
        }

        t = tl;
    }

    // --- compose: out = A0 + L0*(A1 + L1*(A2 + L2*(A3 + L3))) --------------
    if (seg > 0) {
        lds[(seg - 1) * 64 + lane] = make_float4(ar, ag, ab, light);
    }
    __syncthreads();
    if (seg == 0) {
        float4 s1 = lds[0 * 64 + lane];
        float4 s2 = lds[1 * 64 + lane];
        float4 s3 = lds[2 * 64 + lane];
        float r3 = s3.x + s3.w, g3 = s3.y + s3.w, b3 = s3.z + s3.w;
        float r2 = fmaf(s2.w, r3, s2.x);
        float g2 = fmaf(s2.w, g3, s2.y);
        float b2 = fmaf(s2.w, b3, s2.z);
        float r1 = fmaf(s1.w, r2, s1.x);
        float g1 = fmaf(s1.w, g2, s1.y);
        float b1 = fmaf(s1.w, b2, s1.z);
        out[3 * i + 0] = fmaf(light, r1, ar);
        out[3 * i + 1] = fmaf(light, g1, ag);
        out[3 * i + 2] = fmaf(light, b1, ab);
    }
}

// ---- fallback: render straight from fp32 grid (if ws too small) ------------
__global__ __launch_bounds__(256) void volrend_f32(
    const float* __restrict__ grid,
    const float* __restrict__ origins,
    const float* __restrict__ dirs,
    float* __restrict__ out,
    int B)
{
    int i = blockIdx.x * blockDim.x + threadIdx.x;
    if (i >= B) return;

    float oxR, oyR, ozR, dxR, dyR, dzR, ix, iy, iz, ipx, ipy, ipz, tmin, tmax;
    ray_setup(origins, dirs, i, oxR, oyR, ozR, dxR, dyR, dzR,
              ix, iy, iz, ipx, ipy, ipz, tmin, tmax);

    const float4* __restrict__ g4 = (const float4*)grid;

    float t = tmin;
    float light = 1.0f;
    float ar = 0.0f, ag = 0.0f, ab = 0.0f;

    for (int chunk = 0; chunk < N_STEPS / PIPE; ++chunk) {
        if (t >= tmax) break;

        float4 val[PIPE];
        float del[PIPE];
        float tl = t;

        #pragma unroll
        for (int p = 0; p < PIPE; ++p) {
            int i0, i1, i2; float d;
            geom_step(tl, tmax, oxR, oyR, ozR, dxR, dyR, dzR,
                      ix, iy, iz, ipx, ipy, ipz, i0, i1, i2, d);
            val[p] = g4[(i0 * R_DIM + i1) * R_DIM + i2];
            del[p] = d;
            tl = __fadd_rn(tl, d);
        }

        #pragma unroll
        for (int p = 0; p < PIPE; ++p) {
            float sigma = fmaxf(val[p].w, 0.0f);
            float att = __expf(-del[p] * sigma);
            float w = light * (1.0f - att);
            ar = fmaf(w, sigmoid_fast(val[p].x), ar);
            ag = fmaf(w, sigmoid_fast(val[p].y), ag);
            ab = fmaf(w, sigmoid_fast(val[p].z), ab);
            light *= att;
        }

        t = tl;
    }

    out[3 * i + 0] = ar + light;
    out[3 * i + 1] = ag + light;
    out[3 * i + 2] = ab + light;
}

extern "C" void kernel_launch(void* const* d_in, const int* in_sizes, int n_in,
                              void* d_out, int out_size, void* d_ws, size_t ws_size,
                              hipStream_t stream) {
    const float* grid    = (const float*)d_in[0];
    const float* origins = (const float*)d_in[1];
    const float* dirs    = (const float*)d_in[2];
    float* out = (float*)d_out;

    int B = in_sizes[1] / 3;

    size_t need = (size_t)N_VOX * 4 + (size_t)3 * B * 4;   // bricks + cp
    if (ws_size >= need && (B % 64) == 0) {
        uint4* gq4 = (uint4*)d_ws;
        float* cp  = (float*)((char*)d_ws + (size_t)N_VOX * 4);
        int walk_blocks = (B + 255) / 256;
        prep<<<walk_blocks + CVT_BLOCKS, 256, 0, stream>>>(
            (const float4*)grid, gq4, origins, dirs, cp, B, walk_blocks);
        volrend_seg<<<B / 64, 64 * NSEG, 0, stream>>>(
            (const unsigned int*)gq4, cp, origins, dirs, out, B);
    } else {
        volrend_f32<<<(B + 255) / 256, 256, 0, stream>>>(grid, origins, dirs,
                                                         out, B);
    }
}